// Round 1
// baseline (280.529 us; speedup 1.0000x reference)
//
#include <hip/hip_runtime.h>
#include <cstddef>

#define T_DIM 2048
#define B_DIM 64
#define I_DIM 128
#define H_DIM 128
#define FC_DIM 32
#define O_DIM 2

#define NC 4                 // time chunks (parallel affine scan)
#define TC (T_DIM / NC)      // 512 timesteps per chunk
#define MT (TC / 16)         // 32 m-tiles of 16 timesteps

typedef __attribute__((ext_vector_type(8))) short bf16x8;
typedef __attribute__((ext_vector_type(4))) float f32x4;

__device__ __forceinline__ short f2bf(float f) {
    union { float f; unsigned u; } v; v.f = f;
    unsigned r = (v.u + 0x7FFFu + ((v.u >> 16) & 1u)) >> 16;  // RNE
    return (short)r;
}

__device__ __forceinline__ float bf2f(short s) {
    union { unsigned u; float f; } v;
    v.u = ((unsigned)(unsigned short)s) << 16;
    return v.f;
}

// load 8 contiguous floats, produce hi/lo bf16 split fragments
__device__ __forceinline__ void cvt_pair8(const float* __restrict__ p, bf16x8& hi, bf16x8& lo) {
    float4 u0 = *(const float4*)(p);
    float4 u1 = *(const float4*)(p + 4);
    float a[8] = {u0.x, u0.y, u0.z, u0.w, u1.x, u1.y, u1.z, u1.w};
#pragma unroll
    for (int j = 0; j < 8; ++j) {
        short hb = f2bf(a[j]);
        hi[j] = hb;
        lo[j] = f2bf(a[j] - bf2f(hb));
    }
}

__device__ __forceinline__ float fast_sig(float x) {
    return __builtin_amdgcn_rcpf(1.0f + __expf(-x));
}
__device__ __forceinline__ float fast_tanh(float x) {
    return 2.0f * __builtin_amdgcn_rcpf(1.0f + __expf(-2.0f * x)) - 1.0f;
}

// Kernel 1: per (h-half, chunk, b): gate preacts via bf16 MFMA (hi/lo split),
// activations, ordered affine-scan over the chunk -> (F, A) per (b,h).
__global__ void gates_scan_kernel(const float* __restrict__ x,
    const float* __restrict__ w_ig, const float* __restrict__ w_ii,
    const float* __restrict__ w_if,
    const float* __restrict__ b_g, const float* __restrict__ b_i,
    const float* __restrict__ b_f,
    float* __restrict__ wsF, float* __restrict__ wsA)
{
    const int lane = threadIdx.x & 63;
    const int wave = threadIdx.x >> 6;
    const int col  = lane & 15;   // A-operand m-row / B-operand n-col / D col
    const int quad = lane >> 4;   // k-offset selector / D row-block
    const int b = blockIdx.z;
    const int chunk = blockIdx.y;
    const int h = blockIdx.x * 64 + wave * 16 + col;  // this lane's hidden unit (as B n-col)

    // B-fragments (weights) held in registers for the whole kernel.
    // B[n=lane&15][k = quad*8 + j]; w is [b][h][i] row-major -> 8 contiguous i.
    bf16x8 wgh[4], wgl[4], wih[4], wil[4], wfh[4], wfl[4];
    {
        const float* pg = w_ig + ((size_t)b * H_DIM + h) * I_DIM + quad * 8;
        const float* pi = w_ii + ((size_t)b * H_DIM + h) * I_DIM + quad * 8;
        const float* pf = w_if + ((size_t)b * H_DIM + h) * I_DIM + quad * 8;
#pragma unroll
        for (int k = 0; k < 4; ++k) {
            cvt_pair8(pg + k * 32, wgh[k], wgl[k]);
            cvt_pair8(pi + k * 32, wih[k], wil[k]);
            cvt_pair8(pf + k * 32, wfh[k], wfl[k]);
        }
    }
    const float biasg = b_g[b * H_DIM + h];
    const float biasi = b_i[b * H_DIM + h];
    const float biasf = b_f[b * H_DIM + h];

    float Fr = 1.0f, Ar = 0.0f;  // running affine over the chunk (identity)

    const float* xb = x + (size_t)b * I_DIM + (size_t)quad * 8;

    for (int mt = 0; mt < MT; ++mt) {
        // A-fragment rows: m = lane&15 -> timestep t0 + col
        const int trow = chunk * TC + mt * 16 + col;
        const float* xp = xb + (size_t)trow * (B_DIM * I_DIM);
        f32x4 accg = {0.f, 0.f, 0.f, 0.f};
        f32x4 acci = {0.f, 0.f, 0.f, 0.f};
        f32x4 accf = {0.f, 0.f, 0.f, 0.f};
#pragma unroll
        for (int k = 0; k < 4; ++k) {
            bf16x8 ah, al;
            cvt_pair8(xp + k * 32, ah, al);
            accg = __builtin_amdgcn_mfma_f32_16x16x32_bf16(ah, wgh[k], accg, 0, 0, 0);
            acci = __builtin_amdgcn_mfma_f32_16x16x32_bf16(ah, wih[k], acci, 0, 0, 0);
            accf = __builtin_amdgcn_mfma_f32_16x16x32_bf16(ah, wfh[k], accf, 0, 0, 0);
            accg = __builtin_amdgcn_mfma_f32_16x16x32_bf16(al, wgh[k], accg, 0, 0, 0);
            acci = __builtin_amdgcn_mfma_f32_16x16x32_bf16(al, wih[k], acci, 0, 0, 0);
            accf = __builtin_amdgcn_mfma_f32_16x16x32_bf16(al, wfh[k], accf, 0, 0, 0);
            accg = __builtin_amdgcn_mfma_f32_16x16x32_bf16(ah, wgl[k], accg, 0, 0, 0);
            acci = __builtin_amdgcn_mfma_f32_16x16x32_bf16(ah, wil[k], acci, 0, 0, 0);
            accf = __builtin_amdgcn_mfma_f32_16x16x32_bf16(ah, wfl[k], accf, 0, 0, 0);
        }
        // D layout: row = quad*4 + r (ascending t), col = lane&15 (h).
        float Ft, At;
#pragma unroll
        for (int r = 0; r < 4; ++r) {
            float g  = fast_tanh(accg[r] + biasg);
            float iv = fast_sig(acci[r] + biasi);
            float fv = fast_sig(accf[r] + biasf);
            float av = iv * g;
            if (r == 0) { Ft = fv; At = av; }
            else        { At = fv * At + av; Ft = fv * Ft; }
        }
        // ordered combine across quads (quad 0 earliest t): compose(first,then)=(f2*f1, f2*a1+a2)
        float Fo = __shfl_xor(Ft, 16, 64);
        float Ao = __shfl_xor(At, 16, 64);
        if ((quad & 1) == 0) { At = Fo * At + Ao; Ft = Fo * Ft; }
        else                 { At = Ft * Ao + At; Ft = Ft * Fo; }
        Fo = __shfl_xor(Ft, 32, 64);
        Ao = __shfl_xor(At, 32, 64);
        if (quad < 2) { At = Fo * At + Ao; Ft = Fo * Ft; }
        else          { At = Ft * Ao + At; Ft = Ft * Fo; }

        // fold tile into running chunk affine (tile is later in t)
        Ar = Ft * Ar + At;
        Fr = Ft * Fr;
    }

    if (quad == 0) {  // all quads hold identical state; one writer per h
        const int idx = (b * NC + chunk) * H_DIM + h;
        wsF[idx] = Fr;
        wsA[idx] = Ar;
    }
}

// Kernel 2: fold NC chunk-affines -> c_fin; o-gate at t=T-1 (fp32 dot);
// h_fin = o*tanh(c); classifier + log_softmax. One block per batch.
__global__ void finish_kernel(const float* __restrict__ x,
    const float* __restrict__ w_io, const float* __restrict__ b_o,
    const float* __restrict__ fc1_w, const float* __restrict__ fc1_b,
    const float* __restrict__ fc2_w, const float* __restrict__ fc2_b,
    const float* __restrict__ wsF, const float* __restrict__ wsA,
    float* __restrict__ out)
{
    const int b = blockIdx.x;
    const int h = threadIdx.x;  // 128 threads
    __shared__ float hf[H_DIM];
    __shared__ float z1[FC_DIM];

    float c = 0.0f;  // c0 = 0
#pragma unroll
    for (int nc = 0; nc < NC; ++nc) {
        const int idx = (b * NC + nc) * H_DIM + h;
        c = wsF[idx] * c + wsA[idx];
    }
    const float* xl = x + ((size_t)(T_DIM - 1) * B_DIM + b) * I_DIM;
    const float* wo = w_io + ((size_t)b * H_DIM + h) * I_DIM;
    float acc = b_o[b * H_DIM + h];
#pragma unroll 8
    for (int i = 0; i < I_DIM; i += 4) {
        float4 xa = *(const float4*)(xl + i);
        float4 wa = *(const float4*)(wo + i);
        acc += xa.x * wa.x + xa.y * wa.y + xa.z * wa.z + xa.w * wa.w;
    }
    const float o = 1.0f / (1.0f + expf(-acc));
    hf[h] = o * tanhf(c);
    __syncthreads();

    if (h < FC_DIM) {
        float a = fc1_b[h];
        const float* w1 = fc1_w + h * H_DIM;
        for (int i = 0; i < H_DIM; ++i) a += w1[i] * hf[i];
        z1[h] = tanhf(a);
    }
    __syncthreads();

    if (h == 0) {
        float z0 = fc2_b[0], zo1 = fc2_b[1];
        for (int j = 0; j < FC_DIM; ++j) {
            z0  += fc2_w[j] * z1[j];
            zo1 += fc2_w[FC_DIM + j] * z1[j];
        }
        const float m = fmaxf(z0, zo1);
        const float lse = m + logf(expf(z0 - m) + expf(zo1 - m));
        out[b * O_DIM + 0] = z0 - lse;
        out[b * O_DIM + 1] = zo1 - lse;
    }
}

extern "C" void kernel_launch(void* const* d_in, const int* in_sizes, int n_in,
                              void* d_out, int out_size, void* d_ws, size_t ws_size,
                              hipStream_t stream) {
    const float* x     = (const float*)d_in[0];
    const float* w_ig  = (const float*)d_in[1];
    const float* w_ii  = (const float*)d_in[2];
    const float* w_if  = (const float*)d_in[3];
    const float* w_io  = (const float*)d_in[4];
    // d_in[5..8] = w_hg/w_hi/w_hf/w_ho multiply a zero hidden state -> skipped
    const float* b_g   = (const float*)d_in[9];
    const float* b_i   = (const float*)d_in[10];
    const float* b_f   = (const float*)d_in[11];
    const float* b_o   = (const float*)d_in[12];
    const float* fc1_w = (const float*)d_in[13];
    const float* fc1_b = (const float*)d_in[14];
    const float* fc2_w = (const float*)d_in[15];
    const float* fc2_b = (const float*)d_in[16];

    float* wsF = (float*)d_ws;                       // [B][NC][H]
    float* wsA = wsF + (size_t)B_DIM * NC * H_DIM;   // [B][NC][H]
    float* out = (float*)d_out;

    dim3 grid1(2, NC, B_DIM);   // (h-half, chunk, batch)
    gates_scan_kernel<<<grid1, 256, 0, stream>>>(x, w_ig, w_ii, w_if,
                                                 b_g, b_i, b_f, wsF, wsA);
    finish_kernel<<<B_DIM, 128, 0, stream>>>(x, w_io, b_o, fc1_w, fc1_b,
                                             fc2_w, fc2_b, wsF, wsA, out);
}

// Round 2
// 232.755 us; speedup vs baseline: 1.2053x; 1.2053x over previous
//
#include <hip/hip_runtime.h>
#include <cstddef>

#define T_DIM 2048
#define B_DIM 64
#define I_DIM 128
#define H_DIM 128
#define FC_DIM 32
#define O_DIM 2

#define NC 16                // time chunks (parallel affine scan)
#define TC (T_DIM / NC)      // 128 timesteps per chunk
#define SUB (TC / 4)         // 32 timesteps per quad sub-chunk
#define MT (SUB / 4)         // 8 tiles; each tile gives every quad 4 consecutive t

typedef __attribute__((ext_vector_type(8))) short bf16x8;
typedef __attribute__((ext_vector_type(4))) float f32x4;

__device__ __forceinline__ short f2bf(float f) {
    union { float f; unsigned u; } v; v.f = f;
    unsigned r = (v.u + 0x7FFFu + ((v.u >> 16) & 1u)) >> 16;  // RNE
    return (short)r;
}
__device__ __forceinline__ float bf2f(short s) {
    union { unsigned u; float f; } v;
    v.u = ((unsigned)(unsigned short)s) << 16;
    return v.f;
}

__device__ __forceinline__ float fast_sig(float x) {
    return __builtin_amdgcn_rcpf(1.0f + __expf(-x));
}
__device__ __forceinline__ float fast_tanh(float x) {
    return 2.0f * __builtin_amdgcn_rcpf(1.0f + __expf(-2.0f * x)) - 1.0f;
}

// Pass 0a: x fp32 -> bf16 hi + bf16 lo arrays (same [t][b][i] layout).
__global__ void convert_x_kernel(const float* __restrict__ x,
                                 short* __restrict__ xh, short* __restrict__ xl)
{
    const size_t idx = ((size_t)blockIdx.x * 256 + threadIdx.x) * 8;
    float4 u0 = *(const float4*)(x + idx);
    float4 u1 = *(const float4*)(x + idx + 4);
    float a[8] = {u0.x, u0.y, u0.z, u0.w, u1.x, u1.y, u1.z, u1.w};
    bf16x8 hi, lo;
#pragma unroll
    for (int j = 0; j < 8; ++j) {
        short hb = f2bf(a[j]);
        hi[j] = hb;
        lo[j] = f2bf(a[j] - bf2f(hb));
    }
    *(bf16x8*)(xh + idx) = hi;
    *(bf16x8*)(xl + idx) = lo;
}

// Pass 0b: gate weights fp32 -> bf16 (hi only), layout preserved [b][h][i].
__global__ void convert_w_kernel(const float* __restrict__ wg,
                                 const float* __restrict__ wi,
                                 const float* __restrict__ wf,
                                 short* __restrict__ og,
                                 short* __restrict__ oi,
                                 short* __restrict__ of)
{
    const float* src = (blockIdx.y == 0) ? wg : (blockIdx.y == 1) ? wi : wf;
    short* dst       = (blockIdx.y == 0) ? og : (blockIdx.y == 1) ? oi : of;
    const size_t idx = ((size_t)blockIdx.x * 256 + threadIdx.x) * 8;
    float4 u0 = *(const float4*)(src + idx);
    float4 u1 = *(const float4*)(src + idx + 4);
    float a[8] = {u0.x, u0.y, u0.z, u0.w, u1.x, u1.y, u1.z, u1.w};
    bf16x8 hi;
#pragma unroll
    for (int j = 0; j < 8; ++j) hi[j] = f2bf(a[j]);
    *(bf16x8*)(dst + idx) = hi;
}

// Pass 1: per (h-half, chunk, b): gate preacts via bf16 MFMA (x hi+lo, w hi),
// activations, per-quad affine over its 32-t sub-chunk, one cross-quad
// combine at the end -> (F, A) per (b, chunk, h).
__global__ __launch_bounds__(256, 4)
void gates_scan_kernel(const short* __restrict__ xh, const short* __restrict__ xl,
    const short* __restrict__ wg, const short* __restrict__ wi,
    const short* __restrict__ wf,
    const float* __restrict__ b_g, const float* __restrict__ b_i,
    const float* __restrict__ b_f,
    float* __restrict__ wsF, float* __restrict__ wsA)
{
    const int lane = threadIdx.x & 63;
    const int wave = threadIdx.x >> 6;
    const int col  = lane & 15;   // A m-row sel / B n-col / D col
    const int quad = lane >> 4;   // A k-slice sel / D row-block (= t sub-chunk)
    const int b = blockIdx.z;
    const int chunk = blockIdx.y;
    const int h = blockIdx.x * 64 + wave * 16 + col;

    // B-fragments (bf16 weights) in registers: B[n=col][k=quad*8+j]
    bf16x8 Bg[4], Bi[4], Bf[4];
    {
        const size_t wo = ((size_t)b * H_DIM + h) * I_DIM + quad * 8;
#pragma unroll
        for (int kk = 0; kk < 4; ++kk) {
            Bg[kk] = *(const bf16x8*)(wg + wo + kk * 32);
            Bi[kk] = *(const bf16x8*)(wi + wo + kk * 32);
            Bf[kk] = *(const bf16x8*)(wf + wo + kk * 32);
        }
    }
    const float biasg = b_g[b * H_DIM + h];
    const float biasi = b_i[b * H_DIM + h];
    const float biasf = b_f[b * H_DIM + h];

    // A-row m -> timestep: t(m) = chunk*TC + (m>>2)*SUB + mt*4 + (m&3)
    const int tcol = chunk * TC + (col >> 2) * SUB + (col & 3);
    const size_t abase = ((size_t)tcol * B_DIM + b) * I_DIM + quad * 8;

    float Fq = 1.0f, Aq = 0.0f;  // this quad's running affine over its sub-chunk

    for (int mt = 0; mt < MT; ++mt) {
        const size_t a0 = abase + (size_t)mt * 4 * (B_DIM * I_DIM);
        bf16x8 ah[4], al[4];
#pragma unroll
        for (int kk = 0; kk < 4; ++kk) {
            ah[kk] = *(const bf16x8*)(xh + a0 + kk * 32);
            al[kk] = *(const bf16x8*)(xl + a0 + kk * 32);
        }
        f32x4 accg = {0.f, 0.f, 0.f, 0.f};
        f32x4 acci = {0.f, 0.f, 0.f, 0.f};
        f32x4 accf = {0.f, 0.f, 0.f, 0.f};
#pragma unroll
        for (int kk = 0; kk < 4; ++kk) {
            accg = __builtin_amdgcn_mfma_f32_16x16x32_bf16(ah[kk], Bg[kk], accg, 0, 0, 0);
            acci = __builtin_amdgcn_mfma_f32_16x16x32_bf16(ah[kk], Bi[kk], acci, 0, 0, 0);
            accf = __builtin_amdgcn_mfma_f32_16x16x32_bf16(ah[kk], Bf[kk], accf, 0, 0, 0);
            accg = __builtin_amdgcn_mfma_f32_16x16x32_bf16(al[kk], Bg[kk], accg, 0, 0, 0);
            acci = __builtin_amdgcn_mfma_f32_16x16x32_bf16(al[kk], Bi[kk], acci, 0, 0, 0);
            accf = __builtin_amdgcn_mfma_f32_16x16x32_bf16(al[kk], Bf[kk], accf, 0, 0, 0);
        }
        // D row = quad*4 + r -> t = chunk*TC + quad*SUB + mt*4 + r (ascending).
#pragma unroll
        for (int r = 0; r < 4; ++r) {
            float g  = fast_tanh(accg[r] + biasg);
            float iv = fast_sig(acci[r] + biasi);
            float fv = fast_sig(accf[r] + biasf);
            Aq = fv * Aq + iv * g;
            Fq = fv * Fq;
        }
    }

    // Ordered cross-quad combine (quad q covers t-range q*SUB..): 2 rounds.
    float Fo = __shfl_xor(Fq, 16, 64);
    float Ao = __shfl_xor(Aq, 16, 64);
    if ((quad & 1) == 0) { Aq = Fo * Aq + Ao; Fq = Fo * Fq; }
    else                 { Aq = Fq * Ao + Aq; Fq = Fq * Fo; }
    Fo = __shfl_xor(Fq, 32, 64);
    Ao = __shfl_xor(Aq, 32, 64);
    if (quad < 2) { Aq = Fo * Aq + Ao; Fq = Fo * Fq; }
    else          { Aq = Fq * Ao + Aq; Fq = Fq * Fo; }

    if (quad == 0) {
        const int idx = (b * NC + chunk) * H_DIM + h;
        wsF[idx] = Fq;
        wsA[idx] = Aq;
    }
}

// Pass 2: fold NC chunk-affines -> c_fin; o-gate at t=T-1 (fp32 dot);
// h_fin = o*tanh(c); classifier + log_softmax. One block per batch.
__global__ void finish_kernel(const float* __restrict__ x,
    const float* __restrict__ w_io, const float* __restrict__ b_o,
    const float* __restrict__ fc1_w, const float* __restrict__ fc1_b,
    const float* __restrict__ fc2_w, const float* __restrict__ fc2_b,
    const float* __restrict__ wsF, const float* __restrict__ wsA,
    float* __restrict__ out)
{
    const int b = blockIdx.x;
    const int h = threadIdx.x;  // 128 threads
    __shared__ float hf[H_DIM];
    __shared__ float z1[FC_DIM];

    float c = 0.0f;
#pragma unroll
    for (int nc = 0; nc < NC; ++nc) {
        const int idx = (b * NC + nc) * H_DIM + h;
        c = wsF[idx] * c + wsA[idx];
    }
    const float* xl = x + ((size_t)(T_DIM - 1) * B_DIM + b) * I_DIM;
    const float* wo = w_io + ((size_t)b * H_DIM + h) * I_DIM;
    float acc = b_o[b * H_DIM + h];
#pragma unroll 8
    for (int i = 0; i < I_DIM; i += 4) {
        float4 xa = *(const float4*)(xl + i);
        float4 wa = *(const float4*)(wo + i);
        acc += xa.x * wa.x + xa.y * wa.y + xa.z * wa.z + xa.w * wa.w;
    }
    const float o = 1.0f / (1.0f + expf(-acc));
    hf[h] = o * tanhf(c);
    __syncthreads();

    if (h < FC_DIM) {
        float a = fc1_b[h];
        const float* w1 = fc1_w + h * H_DIM;
        for (int i = 0; i < H_DIM; ++i) a += w1[i] * hf[i];
        z1[h] = tanhf(a);
    }
    __syncthreads();

    if (h == 0) {
        float z0 = fc2_b[0], zo1 = fc2_b[1];
        for (int j = 0; j < FC_DIM; ++j) {
            z0  += fc2_w[j] * z1[j];
            zo1 += fc2_w[FC_DIM + j] * z1[j];
        }
        const float m = fmaxf(z0, zo1);
        const float lse = m + logf(expf(z0 - m) + expf(zo1 - m));
        out[b * O_DIM + 0] = z0 - lse;
        out[b * O_DIM + 1] = zo1 - lse;
    }
}

extern "C" void kernel_launch(void* const* d_in, const int* in_sizes, int n_in,
                              void* d_out, int out_size, void* d_ws, size_t ws_size,
                              hipStream_t stream) {
    const float* x     = (const float*)d_in[0];
    const float* w_ig  = (const float*)d_in[1];
    const float* w_ii  = (const float*)d_in[2];
    const float* w_if  = (const float*)d_in[3];
    const float* w_io  = (const float*)d_in[4];
    // d_in[5..8] = w_hg/w_hi/w_hf/w_ho multiply a zero hidden state -> skipped
    const float* b_g   = (const float*)d_in[9];
    const float* b_i   = (const float*)d_in[10];
    const float* b_f   = (const float*)d_in[11];
    const float* b_o   = (const float*)d_in[12];
    const float* fc1_w = (const float*)d_in[13];
    const float* fc1_b = (const float*)d_in[14];
    const float* fc2_w = (const float*)d_in[15];
    const float* fc2_b = (const float*)d_in[16];

    // Workspace partition (bytes):
    //  xh: T*B*I shorts = 33,554,432 B
    //  xl: 33,554,432 B
    //  wg/wi/wf: 3 x B*H*I shorts = 3 x 2,097,152 B
    //  wsF/wsA: 2 x B*NC*H floats = 2 x 524,288 B
    const size_t NX = (size_t)T_DIM * B_DIM * I_DIM;    // 16,777,216
    const size_t NW = (size_t)B_DIM * H_DIM * I_DIM;    // 1,048,576
    short* xh = (short*)d_ws;
    short* xli = xh + NX;
    short* wgc = xli + NX;
    short* wic = wgc + NW;
    short* wfc = wic + NW;
    float* wsF = (float*)(wfc + NW);
    float* wsA = wsF + (size_t)B_DIM * NC * H_DIM;
    float* out = (float*)d_out;

    convert_x_kernel<<<dim3(NX / (256 * 8)), 256, 0, stream>>>(x, xh, xli);
    convert_w_kernel<<<dim3(NW / (256 * 8), 3), 256, 0, stream>>>(
        w_ig, w_ii, w_if, wgc, wic, wfc);

    dim3 grid1(2, NC, B_DIM);   // (h-half, chunk, batch)
    gates_scan_kernel<<<grid1, 256, 0, stream>>>(xh, xli, wgc, wic, wfc,
                                                 b_g, b_i, b_f, wsF, wsA);
    finish_kernel<<<B_DIM, 128, 0, stream>>>(x, w_io, b_o, fc1_w, fc1_b,
                                             fc2_w, fc2_b, wsF, wsA, out);
}

// Round 3
// 165.390 us; speedup vs baseline: 1.6962x; 1.4073x over previous
//
#include <hip/hip_runtime.h>
#include <cstddef>

#define T_DIM 2048
#define B_DIM 64
#define I_DIM 128
#define H_DIM 128
#define FC_DIM 32
#define O_DIM 2

#define NC 16                // time chunks (parallel affine scan)
#define TC (T_DIM / NC)      // 128 timesteps per chunk
#define MT 8                 // 8 m-tiles of 16 t per chunk

typedef __attribute__((ext_vector_type(8))) short bf16x8;
typedef __attribute__((ext_vector_type(4))) float f32x4;

__device__ __forceinline__ short f2bf(float f) {
    union { float f; unsigned u; } v; v.f = f;
    unsigned r = (v.u + 0x7FFFu + ((v.u >> 16) & 1u)) >> 16;  // RNE
    return (short)r;
}
__device__ __forceinline__ float bf2f(short s) {
    union { unsigned u; float f; } v;
    v.u = ((unsigned)(unsigned short)s) << 16;
    return v.f;
}
__device__ __forceinline__ float fast_sig(float x) {
    return __builtin_amdgcn_rcpf(1.0f + __expf(-x));
}
__device__ __forceinline__ float fast_tanh(float x) {
    return 2.0f * __builtin_amdgcn_rcpf(1.0f + __expf(-2.0f * x)) - 1.0f;
}

// Pass 0: gate weights fp32 -> bf16 (hi only), layout preserved [b][h][i].
__global__ void convert_w_kernel(const float* __restrict__ wg,
                                 const float* __restrict__ wi,
                                 const float* __restrict__ wf,
                                 short* __restrict__ og,
                                 short* __restrict__ oi,
                                 short* __restrict__ of)
{
    const float* src = (blockIdx.y == 0) ? wg : (blockIdx.y == 1) ? wi : wf;
    short* dst       = (blockIdx.y == 0) ? og : (blockIdx.y == 1) ? oi : of;
    const size_t idx = ((size_t)blockIdx.x * 256 + threadIdx.x) * 8;
    float4 u0 = *(const float4*)(src + idx);
    float4 u1 = *(const float4*)(src + idx + 4);
    float a[8] = {u0.x, u0.y, u0.z, u0.w, u1.x, u1.y, u1.z, u1.w};
    bf16x8 hi;
#pragma unroll
    for (int j = 0; j < 8; ++j) hi[j] = f2bf(a[j]);
    *(bf16x8*)(dst + idx) = hi;
}

// Pass 1: one block per (b, chunk), 8 waves covering all 128 h.
// Phase A: waves cooperatively convert the chunk's x slice (fp32, read once)
//          into bf16 hi/lo MFMA A-fragments in LDS (fragment-order layout:
//          lane-contiguous 16B slots -> conflict-free b128 writes & reads).
// Phase B: per m-tile: ds_read frags, 24 MFMA (x hi+lo vs w hi),
//          activations, per-quad affine scan; cross-quad combine at end.
// m-row -> t map within chunk: t(m) = (m>>2)*32 + mt*4 + (m&3), so D rows
// (row = quad*4 + r) give each quad 4 consecutive t per tile; quad q owns
// t-subrange [q*32, q*32+32).
__global__ __launch_bounds__(512, 4)
void gates_scan_kernel(const float* __restrict__ x,
    const short* __restrict__ wg, const short* __restrict__ wi,
    const short* __restrict__ wf,
    const float* __restrict__ b_g, const float* __restrict__ b_i,
    const float* __restrict__ b_f,
    float* __restrict__ wsF, float* __restrict__ wsA)
{
    // frag[mt][hl][kk][lane][8 shorts] = 8*2*4*64*8 shorts = 64 KB
    __shared__ short frag[MT * 2 * 4 * 64 * 8];

    const int L    = threadIdx.x & 63;
    const int wv   = threadIdx.x >> 6;   // 0..7: conversion mt / compute h-group
    const int col  = L & 15;
    const int quad = L >> 4;
    const int bid  = blockIdx.x;
    const int b     = bid & (B_DIM - 1);  // b-minor: same-b blocks 64 apart -> same XCD
    const int chunk = bid >> 6;

    // ---- weight fragments for this wave's 16 h columns: h = wv*16 + col
    const int h = wv * 16 + col;
    bf16x8 Bg[4], Bi[4], Bf[4];
    {
        const size_t wo = ((size_t)b * H_DIM + h) * I_DIM + quad * 8;
#pragma unroll
        for (int kk = 0; kk < 4; ++kk) {
            Bg[kk] = *(const bf16x8*)(wg + wo + kk * 32);
            Bi[kk] = *(const bf16x8*)(wi + wo + kk * 32);
            Bf[kk] = *(const bf16x8*)(wf + wo + kk * 32);
        }
    }
    const float biasg = b_g[b * H_DIM + h];
    const float biasi = b_i[b * H_DIM + h];
    const float biasf = b_f[b * H_DIM + h];

    // ---- Phase A: convert m-tile mt = wv into LDS fragments
    {
        const int mt = wv;
        const int tl = (col >> 2) * 32 + mt * 4 + (col & 3);  // t within chunk
        const float* xp = x + ((size_t)(chunk * TC + tl) * B_DIM + b) * I_DIM;
#pragma unroll
        for (int kk = 0; kk < 4; ++kk) {
            const int i0 = quad * 8 + kk * 32;
            float4 u0 = *(const float4*)(xp + i0);
            float4 u1 = *(const float4*)(xp + i0 + 4);
            float a[8] = {u0.x, u0.y, u0.z, u0.w, u1.x, u1.y, u1.z, u1.w};
            bf16x8 hi, lo;
#pragma unroll
            for (int j = 0; j < 8; ++j) {
                short hb = f2bf(a[j]);
                hi[j] = hb;
                lo[j] = f2bf(a[j] - bf2f(hb));
            }
            *(bf16x8*)(frag + ((((mt * 2 + 0) * 4 + kk) * 64) + L) * 8) = hi;
            *(bf16x8*)(frag + ((((mt * 2 + 1) * 4 + kk) * 64) + L) * 8) = lo;
        }
    }
    __syncthreads();

    // ---- Phase B: MFMA + activations + per-quad scan
    float Fq = 1.0f, Aq = 0.0f;
#pragma unroll 2
    for (int mt = 0; mt < MT; ++mt) {
        bf16x8 ah[4], al[4];
#pragma unroll
        for (int kk = 0; kk < 4; ++kk) {
            ah[kk] = *(const bf16x8*)(frag + ((((mt * 2 + 0) * 4 + kk) * 64) + L) * 8);
            al[kk] = *(const bf16x8*)(frag + ((((mt * 2 + 1) * 4 + kk) * 64) + L) * 8);
        }
        f32x4 accg = {0.f, 0.f, 0.f, 0.f};
        f32x4 acci = {0.f, 0.f, 0.f, 0.f};
        f32x4 accf = {0.f, 0.f, 0.f, 0.f};
#pragma unroll
        for (int kk = 0; kk < 4; ++kk) {
            accg = __builtin_amdgcn_mfma_f32_16x16x32_bf16(ah[kk], Bg[kk], accg, 0, 0, 0);
            acci = __builtin_amdgcn_mfma_f32_16x16x32_bf16(ah[kk], Bi[kk], acci, 0, 0, 0);
            accf = __builtin_amdgcn_mfma_f32_16x16x32_bf16(ah[kk], Bf[kk], accf, 0, 0, 0);
            accg = __builtin_amdgcn_mfma_f32_16x16x32_bf16(al[kk], Bg[kk], accg, 0, 0, 0);
            acci = __builtin_amdgcn_mfma_f32_16x16x32_bf16(al[kk], Bi[kk], acci, 0, 0, 0);
            accf = __builtin_amdgcn_mfma_f32_16x16x32_bf16(al[kk], Bf[kk], accf, 0, 0, 0);
        }
        // D row = quad*4 + r -> t = quad*32 + mt*4 + r (consecutive per quad)
#pragma unroll
        for (int r = 0; r < 4; ++r) {
            float g  = fast_tanh(accg[r] + biasg);
            float iv = fast_sig(acci[r] + biasi);
            float fv = fast_sig(accf[r] + biasf);
            Aq = fv * Aq + iv * g;
            Fq = fv * Fq;
        }
    }

    // Ordered cross-quad combine (quad q covers t-range q*32..): 2 rounds.
    float Fo = __shfl_xor(Fq, 16, 64);
    float Ao = __shfl_xor(Aq, 16, 64);
    if ((quad & 1) == 0) { Aq = Fo * Aq + Ao; Fq = Fo * Fq; }
    else                 { Aq = Fq * Ao + Aq; Fq = Fq * Fo; }
    Fo = __shfl_xor(Fq, 32, 64);
    Ao = __shfl_xor(Aq, 32, 64);
    if (quad < 2) { Aq = Fo * Aq + Ao; Fq = Fo * Fq; }
    else          { Aq = Fq * Ao + Aq; Fq = Fq * Fo; }

    if (quad == 0) {
        const int idx = (b * NC + chunk) * H_DIM + h;
        wsF[idx] = Fq;
        wsA[idx] = Aq;
    }
}

// Pass 2: fold NC chunk-affines -> c_fin; o-gate at t=T-1 (fp32 dot);
// h_fin = o*tanh(c); classifier + log_softmax. One block per batch.
__global__ void finish_kernel(const float* __restrict__ x,
    const float* __restrict__ w_io, const float* __restrict__ b_o,
    const float* __restrict__ fc1_w, const float* __restrict__ fc1_b,
    const float* __restrict__ fc2_w, const float* __restrict__ fc2_b,
    const float* __restrict__ wsF, const float* __restrict__ wsA,
    float* __restrict__ out)
{
    const int b = blockIdx.x;
    const int h = threadIdx.x;  // 128 threads
    __shared__ float hf[H_DIM];
    __shared__ float z1[FC_DIM];

    float c = 0.0f;
#pragma unroll
    for (int nc = 0; nc < NC; ++nc) {
        const int idx = (b * NC + nc) * H_DIM + h;
        c = wsF[idx] * c + wsA[idx];
    }
    const float* xl = x + ((size_t)(T_DIM - 1) * B_DIM + b) * I_DIM;
    const float* wo = w_io + ((size_t)b * H_DIM + h) * I_DIM;
    float acc = b_o[b * H_DIM + h];
#pragma unroll 8
    for (int i = 0; i < I_DIM; i += 4) {
        float4 xa = *(const float4*)(xl + i);
        float4 wa = *(const float4*)(wo + i);
        acc += xa.x * wa.x + xa.y * wa.y + xa.z * wa.z + xa.w * wa.w;
    }
    const float o = 1.0f / (1.0f + expf(-acc));
    hf[h] = o * tanhf(c);
    __syncthreads();

    if (h < FC_DIM) {
        float a = fc1_b[h];
        const float* w1 = fc1_w + h * H_DIM;
        for (int i = 0; i < H_DIM; ++i) a += w1[i] * hf[i];
        z1[h] = tanhf(a);
    }
    __syncthreads();

    if (h == 0) {
        float z0 = fc2_b[0], zo1 = fc2_b[1];
        for (int j = 0; j < FC_DIM; ++j) {
            z0  += fc2_w[j] * z1[j];
            zo1 += fc2_w[FC_DIM + j] * z1[j];
        }
        const float m = fmaxf(z0, zo1);
        const float lse = m + logf(expf(z0 - m) + expf(zo1 - m));
        out[b * O_DIM + 0] = z0 - lse;
        out[b * O_DIM + 1] = zo1 - lse;
    }
}

extern "C" void kernel_launch(void* const* d_in, const int* in_sizes, int n_in,
                              void* d_out, int out_size, void* d_ws, size_t ws_size,
                              hipStream_t stream) {
    const float* x     = (const float*)d_in[0];
    const float* w_ig  = (const float*)d_in[1];
    const float* w_ii  = (const float*)d_in[2];
    const float* w_if  = (const float*)d_in[3];
    const float* w_io  = (const float*)d_in[4];
    // d_in[5..8] = w_hg/w_hi/w_hf/w_ho multiply a zero hidden state -> skipped
    const float* b_g   = (const float*)d_in[9];
    const float* b_i   = (const float*)d_in[10];
    const float* b_f   = (const float*)d_in[11];
    const float* b_o   = (const float*)d_in[12];
    const float* fc1_w = (const float*)d_in[13];
    const float* fc1_b = (const float*)d_in[14];
    const float* fc2_w = (const float*)d_in[15];
    const float* fc2_b = (const float*)d_in[16];

    // Workspace: wg/wi/wf bf16 (3 x 2 MB) + wsF/wsA (2 x 4 MB/8... 2 x 512 KB)
    const size_t NW = (size_t)B_DIM * H_DIM * I_DIM;    // 1,048,576
    short* wgc = (short*)d_ws;
    short* wic = wgc + NW;
    short* wfc = wic + NW;
    float* wsF = (float*)(wfc + NW);
    float* wsA = wsF + (size_t)B_DIM * NC * H_DIM;
    float* out = (float*)d_out;

    convert_w_kernel<<<dim3(NW / (256 * 8), 3), 256, 0, stream>>>(
        w_ig, w_ii, w_if, wgc, wic, wfc);

    // bid = chunk*64 + b (b-minor => per-b weight reuse within an XCD)
    gates_scan_kernel<<<dim3(B_DIM * NC), 512, 0, stream>>>(
        x, wgc, wic, wfc, b_g, b_i, b_f, wsF, wsA);

    finish_kernel<<<B_DIM, 128, 0, stream>>>(x, w_io, b_o, fc1_w, fc1_b,
                                             fc2_w, fc2_b, wsF, wsA, out);
}

// Round 4
// 156.312 us; speedup vs baseline: 1.7947x; 1.0581x over previous
//
#include <hip/hip_runtime.h>
#include <hip/hip_bf16.h>
#include <cstddef>

#define T_DIM 2048
#define B_DIM 64
#define I_DIM 128
#define H_DIM 128
#define FC_DIM 32
#define O_DIM 2

#define NC 16                // time chunks (parallel affine scan)
#define TC (T_DIM / NC)      // 128 timesteps per chunk
#define MT 8                 // 8 m-tiles of 16 t per chunk

#define LOG2E  1.44269504088896f
#define LOG2E2 2.88539008177793f

typedef __attribute__((ext_vector_type(8))) short bf16x8;
typedef __attribute__((ext_vector_type(4))) float f32x4;

// packed fp32x8 -> bf16x8 (RNE) via v_cvt_pk_bf16_f32
__device__ __forceinline__ bf16x8 cvt8(const float* __restrict__ p) {
    union { bf16x8 v; __hip_bfloat162 h2[4]; } u;
#pragma unroll
    for (int j = 0; j < 4; ++j) {
        float2 f2 = {p[2 * j], p[2 * j + 1]};
        u.h2[j] = __float22bfloat162_rn(f2);
    }
    return u.v;
}

// Pass 0: gate weights fp32 -> bf16, pre-scaled by log2e factors so the
// gates kernel can use exp2 directly. Layout preserved [b][h][i].
__global__ void convert_w_kernel(const float* __restrict__ wg,
                                 const float* __restrict__ wi,
                                 const float* __restrict__ wf,
                                 short* __restrict__ og,
                                 short* __restrict__ oi,
                                 short* __restrict__ of)
{
    const float* src = (blockIdx.y == 0) ? wg : (blockIdx.y == 1) ? wi : wf;
    short* dst       = (blockIdx.y == 0) ? og : (blockIdx.y == 1) ? oi : of;
    const float scale = (blockIdx.y == 0) ? LOG2E2 : LOG2E;
    const size_t idx = ((size_t)blockIdx.x * 256 + threadIdx.x) * 8;
    float4 u0 = *(const float4*)(src + idx);
    float4 u1 = *(const float4*)(src + idx + 4);
    float a[8] = {u0.x * scale, u0.y * scale, u0.z * scale, u0.w * scale,
                  u1.x * scale, u1.y * scale, u1.z * scale, u1.w * scale};
    *(bf16x8*)(dst + idx) = cvt8(a);
}

// Pass 1: one block per (b, chunk), 8 waves covering all 128 h.
// Phase A: waves cooperatively convert the chunk's x slice (fp32, read once)
//          into bf16 MFMA A-fragments in LDS (fragment-order layout ->
//          conflict-free b128 writes & reads).
// Phase B: per m-tile: 4 ds_read_b128, 12 MFMA, exp2-based activations,
//          per-quad affine scan; cross-quad combine at end.
// m-row -> t map within chunk: t(m) = (m>>2)*32 + mt*4 + (m&3); D rows
// (row = quad*4 + r) give each quad 4 consecutive t; quad q owns [q*32, q*32+32).
__global__ __launch_bounds__(512, 4)
void gates_scan_kernel(const float* __restrict__ x,
    const short* __restrict__ wg, const short* __restrict__ wi,
    const short* __restrict__ wf,
    const float* __restrict__ b_g, const float* __restrict__ b_i,
    const float* __restrict__ b_f,
    float* __restrict__ wsF, float* __restrict__ wsA)
{
    // frag[mt][kk][lane][8 shorts] = 8*4*64*8 shorts = 32 KB
    __shared__ short frag[MT * 4 * 64 * 8];

    const int L    = threadIdx.x & 63;
    const int wv   = threadIdx.x >> 6;   // 0..7: conversion mt / compute h-group
    const int col  = L & 15;
    const int quad = L >> 4;
    const int bid  = blockIdx.x;
    const int b     = bid & (B_DIM - 1);  // b-minor: same-b blocks 64 apart -> same XCD
    const int chunk = bid >> 6;

    // ---- weight fragments for this wave's 16 h columns: h = wv*16 + col
    const int h = wv * 16 + col;
    bf16x8 Bg[4], Bi[4], Bf[4];
    {
        const size_t wo = ((size_t)b * H_DIM + h) * I_DIM + quad * 8;
#pragma unroll
        for (int kk = 0; kk < 4; ++kk) {
            Bg[kk] = *(const bf16x8*)(wg + wo + kk * 32);
            Bi[kk] = *(const bf16x8*)(wi + wo + kk * 32);
            Bf[kk] = *(const bf16x8*)(wf + wo + kk * 32);
        }
    }
    const float biasg = b_g[b * H_DIM + h] * LOG2E2;
    const float biasi = b_i[b * H_DIM + h] * LOG2E;
    const float biasf = b_f[b * H_DIM + h] * LOG2E;

    // ---- Phase A: convert m-tile mt = wv into LDS fragments
    {
        const int mt = wv;
        const int tl = (col >> 2) * 32 + mt * 4 + (col & 3);  // t within chunk
        const float* xp = x + ((size_t)(chunk * TC + tl) * B_DIM + b) * I_DIM;
#pragma unroll
        for (int kk = 0; kk < 4; ++kk) {
            const int i0 = quad * 8 + kk * 32;
            float4 u0 = *(const float4*)(xp + i0);
            float4 u1 = *(const float4*)(xp + i0 + 4);
            float a[8] = {u0.x, u0.y, u0.z, u0.w, u1.x, u1.y, u1.z, u1.w};
            *(bf16x8*)(frag + (((mt * 4 + kk) * 64) + L) * 8) = cvt8(a);
        }
    }
    __syncthreads();

    // ---- Phase B: MFMA + activations + per-quad scan
    float Fq = 1.0f, Aq = 0.0f;
#pragma unroll 2
    for (int mt = 0; mt < MT; ++mt) {
        bf16x8 ah[4];
#pragma unroll
        for (int kk = 0; kk < 4; ++kk)
            ah[kk] = *(const bf16x8*)(frag + (((mt * 4 + kk) * 64) + L) * 8);
        f32x4 accg = {0.f, 0.f, 0.f, 0.f};
        f32x4 acci = {0.f, 0.f, 0.f, 0.f};
        f32x4 accf = {0.f, 0.f, 0.f, 0.f};
#pragma unroll
        for (int kk = 0; kk < 4; ++kk) {
            accg = __builtin_amdgcn_mfma_f32_16x16x32_bf16(ah[kk], Bg[kk], accg, 0, 0, 0);
            acci = __builtin_amdgcn_mfma_f32_16x16x32_bf16(ah[kk], Bi[kk], acci, 0, 0, 0);
            accf = __builtin_amdgcn_mfma_f32_16x16x32_bf16(ah[kk], Bf[kk], accf, 0, 0, 0);
        }
        // D row = quad*4 + r -> t = quad*32 + mt*4 + r (consecutive per quad)
#pragma unroll
        for (int r = 0; r < 4; ++r) {
            // preacts pre-scaled by log2e (g by 2*log2e): use exp2 directly
            float g  = 2.0f * __builtin_amdgcn_rcpf(
                           1.0f + __builtin_amdgcn_exp2f(-(accg[r] + biasg))) - 1.0f;
            float iv = __builtin_amdgcn_rcpf(
                           1.0f + __builtin_amdgcn_exp2f(-(acci[r] + biasi)));
            float fv = __builtin_amdgcn_rcpf(
                           1.0f + __builtin_amdgcn_exp2f(-(accf[r] + biasf)));
            Aq = fv * Aq + iv * g;
            Fq = fv * Fq;
        }
    }

    // Ordered cross-quad combine (quad q covers t-range q*32..): 2 rounds.
    float Fo = __shfl_xor(Fq, 16, 64);
    float Ao = __shfl_xor(Aq, 16, 64);
    if ((quad & 1) == 0) { Aq = Fo * Aq + Ao; Fq = Fo * Fq; }
    else                 { Aq = Fq * Ao + Aq; Fq = Fq * Fo; }
    Fo = __shfl_xor(Fq, 32, 64);
    Ao = __shfl_xor(Aq, 32, 64);
    if (quad < 2) { Aq = Fo * Aq + Ao; Fq = Fo * Fq; }
    else          { Aq = Fq * Ao + Aq; Fq = Fq * Fo; }

    if (quad == 0) {
        const int idx = (b * NC + chunk) * H_DIM + h;
        wsF[idx] = Fq;
        wsA[idx] = Aq;
    }
}

// Pass 2: fold NC chunk-affines -> c_fin; o-gate at t=T-1 (fp32 dot);
// h_fin = o*tanh(c); classifier + log_softmax. One block per batch.
__global__ void finish_kernel(const float* __restrict__ x,
    const float* __restrict__ w_io, const float* __restrict__ b_o,
    const float* __restrict__ fc1_w, const float* __restrict__ fc1_b,
    const float* __restrict__ fc2_w, const float* __restrict__ fc2_b,
    const float* __restrict__ wsF, const float* __restrict__ wsA,
    float* __restrict__ out)
{
    const int b = blockIdx.x;
    const int h = threadIdx.x;  // 128 threads
    __shared__ float hf[H_DIM];
    __shared__ float z1[FC_DIM];

    float c = 0.0f;
#pragma unroll
    for (int nc = 0; nc < NC; ++nc) {
        const int idx = (b * NC + nc) * H_DIM + h;
        c = wsF[idx] * c + wsA[idx];
    }
    const float* xl = x + ((size_t)(T_DIM - 1) * B_DIM + b) * I_DIM;
    const float* wo = w_io + ((size_t)b * H_DIM + h) * I_DIM;
    float acc = b_o[b * H_DIM + h];
#pragma unroll 8
    for (int i = 0; i < I_DIM; i += 4) {
        float4 xa = *(const float4*)(xl + i);
        float4 wa = *(const float4*)(wo + i);
        acc += xa.x * wa.x + xa.y * wa.y + xa.z * wa.z + xa.w * wa.w;
    }
    const float o = 1.0f / (1.0f + expf(-acc));
    hf[h] = o * tanhf(c);
    __syncthreads();

    if (h < FC_DIM) {
        float a = fc1_b[h];
        const float* w1 = fc1_w + h * H_DIM;
        for (int i = 0; i < H_DIM; ++i) a += w1[i] * hf[i];
        z1[h] = tanhf(a);
    }
    __syncthreads();

    if (h == 0) {
        float z0 = fc2_b[0], zo1 = fc2_b[1];
        for (int j = 0; j < FC_DIM; ++j) {
            z0  += fc2_w[j] * z1[j];
            zo1 += fc2_w[FC_DIM + j] * z1[j];
        }
        const float m = fmaxf(z0, zo1);
        const float lse = m + logf(expf(z0 - m) + expf(zo1 - m));
        out[b * O_DIM + 0] = z0 - lse;
        out[b * O_DIM + 1] = zo1 - lse;
    }
}

extern "C" void kernel_launch(void* const* d_in, const int* in_sizes, int n_in,
                              void* d_out, int out_size, void* d_ws, size_t ws_size,
                              hipStream_t stream) {
    const float* x     = (const float*)d_in[0];
    const float* w_ig  = (const float*)d_in[1];
    const float* w_ii  = (const float*)d_in[2];
    const float* w_if  = (const float*)d_in[3];
    const float* w_io  = (const float*)d_in[4];
    // d_in[5..8] = w_hg/w_hi/w_hf/w_ho multiply a zero hidden state -> skipped
    const float* b_g   = (const float*)d_in[9];
    const float* b_i   = (const float*)d_in[10];
    const float* b_f   = (const float*)d_in[11];
    const float* b_o   = (const float*)d_in[12];
    const float* fc1_w = (const float*)d_in[13];
    const float* fc1_b = (const float*)d_in[14];
    const float* fc2_w = (const float*)d_in[15];
    const float* fc2_b = (const float*)d_in[16];

    // Workspace: wg/wi/wf bf16 (3 x 2 MB) + wsF/wsA (2 x 512 KB)
    const size_t NW = (size_t)B_DIM * H_DIM * I_DIM;    // 1,048,576
    short* wgc = (short*)d_ws;
    short* wic = wgc + NW;
    short* wfc = wic + NW;
    float* wsF = (float*)(wfc + NW);
    float* wsA = wsF + (size_t)B_DIM * NC * H_DIM;
    float* out = (float*)d_out;

    convert_w_kernel<<<dim3(NW / (256 * 8), 3), 256, 0, stream>>>(
        w_ig, w_ii, w_if, wgc, wic, wfc);

    // bid = chunk*64 + b (b-minor => per-b weight reuse within an XCD)
    gates_scan_kernel<<<dim3(B_DIM * NC), 512, 0, stream>>>(
        x, wgc, wic, wfc, b_g, b_i, b_f, wsF, wsA);

    finish_kernel<<<B_DIM, 128, 0, stream>>>(x, w_io, b_o, fc1_w, fc1_b,
                                             fc2_w, fc2_b, wsF, wsA, out);
}